// Round 1
// baseline (221.308 us; speedup 1.0000x reference)
//
#include <hip/hip_runtime.h>
#include <math.h>

#define NCLS 91
#define FDIM 256
#define BLOCKS1 256
#define THREADS1 1024
#define WAVES_PER_BLOCK (THREADS1 / 64)
#define TOTAL_WAVES (BLOCKS1 * WAVES_PER_BLOCK)

// ---------------- kernel 1: normalize + segment-sum into global accum ----------------
// LDS bins per block: [NCLS][FDIM] floats in TRANSPOSED slot layout:
//   element d of a class stored at slot (d&3)*64 + (d>>2)
// so that a wave adding its float4 (lane holds d = lane*4..lane*4+3) writes
// consecutive slots per lane per component -> conflict-free ds_add.
extern "C" __global__ void __launch_bounds__(THREADS1)
seg_accum(const float* __restrict__ feats, const int* __restrict__ labels,
          float* __restrict__ g_sums, unsigned int* __restrict__ g_counts,
          int nrows)
{
    extern __shared__ float smem[];
    float* bins = smem;                                  // NCLS*FDIM
    unsigned int* cbins = (unsigned int*)(smem + NCLS * FDIM);   // NCLS

    const int tid = threadIdx.x;
    for (int i = tid; i < NCLS * FDIM; i += THREADS1) bins[i] = 0.0f;
    for (int i = tid; i < NCLS; i += THREADS1) cbins[i] = 0u;
    __syncthreads();

    const int lane = tid & 63;
    const int wave = tid >> 6;
    const int gw = blockIdx.x * WAVES_PER_BLOCK + wave;

    for (int row = gw; row < nrows; row += TOTAL_WAVES) {
        const float4 v = *reinterpret_cast<const float4*>(
            feats + (size_t)row * FDIM + (size_t)lane * 4);
        float ss = v.x * v.x + v.y * v.y + v.z * v.z + v.w * v.w;
        #pragma unroll
        for (int m = 1; m < 64; m <<= 1) ss += __shfl_xor(ss, m, 64);
        const float inv = 1.0f / fmaxf(sqrtf(ss), 1e-12f);

        const int lab = labels[row];
        float* b = bins + lab * FDIM;
        atomicAdd(b + lane,        v.x * inv);   // slot 0*64+lane  (d = lane*4+0)
        atomicAdd(b + 64 + lane,   v.y * inv);   // slot 1*64+lane
        atomicAdd(b + 128 + lane,  v.z * inv);   // slot 2*64+lane
        atomicAdd(b + 192 + lane,  v.w * inv);   // slot 3*64+lane
        if (lane == 0) atomicAdd(&cbins[lab], 1u);
    }

    __syncthreads();
    // flush (g_sums kept in the same transposed slot layout; finalize un-permutes)
    for (int s = tid; s < NCLS * FDIM; s += THREADS1)
        atomicAdd(&g_sums[s], bins[s]);
    for (int i = tid; i < NCLS; i += THREADS1)
        atomicAdd(&g_counts[i], cbins[i]);
}

// ---------------- bool / scalar dtype detection helpers ----------------
// bool inputs may be stored as uint8 (numpy bool), int32, or float32.
// Detect from the first 22 words (88 bytes, in-bounds for 91-elem uint8):
//   int32 {0,1} words  -> enc 1
//   f32 {0.0,1.0} words-> enc 2
//   otherwise uint8    -> enc 0
__device__ int detect_bool_enc(const void* p) {
    const unsigned int* u = (const unsigned int*)p;
    bool i32ok = true, f32ok = true;
    for (int i = 0; i < 22; ++i) {
        unsigned int w = u[i];
        if (w > 1u) i32ok = false;
        if (w != 0u && w != 0x3F800000u) f32ok = false;
    }
    return i32ok ? 1 : (f32ok ? 2 : 0);
}
__device__ bool read_bool(const void* p, int enc, int i) {
    if (enc == 1) return ((const unsigned int*)p)[i] != 0u;
    if (enc == 2) return ((const float*)p)[i] != 0.0f;
    return ((const unsigned char*)p)[i] != 0;
}
__device__ int read_step(const void* p) {
    unsigned int w = ((const unsigned int*)p)[0];
    int iv = (int)w;
    if (iv >= 0 && iv < 16777216) return iv;      // plausible small int
    return (int)__uint_as_float(w);               // else it's a float
}

// ---------------- kernel 2: per-class finalize, writes all 6 outputs as f32 ----------------
extern "C" __global__ void __launch_bounds__(FDIM)
finalize(const float* __restrict__ g_sums, const unsigned int* __restrict__ g_counts,
         const float* __restrict__ protos, const void* __restrict__ p_init,
         const float* __restrict__ p_var, const float* __restrict__ shadow,
         const void* __restrict__ s_init, const int* __restrict__ p_count,
         const void* __restrict__ p_step, float* __restrict__ out)
{
    const int c = blockIdx.x;
    const int d = threadIdx.x;

    __shared__ int enc_pi, enc_si;
    __shared__ float red[FDIM / 64];
    __shared__ float s_upd;
    if (d == 0) { enc_pi = detect_bool_enc(p_init); enc_si = detect_bool_enc(s_init); }
    __syncthreads();

    const unsigned int cnt = g_counts[c];
    const bool present = cnt > 0u;
    // un-permute the transposed slot layout
    const float sum = g_sums[c * FDIM + ((d & 3) << 6) + (d >> 2)];
    const float cls = sum / fmaxf((float)cnt, 1.0f);
    const float oldp = protos[c * FDIM + d];

    // upd_mag = sqrt(sum_d (cls-old)^2 + 1e-24)
    const float diff = cls - oldp;
    float ds = diff * diff;
    #pragma unroll
    for (int m = 1; m < 64; m <<= 1) ds += __shfl_xor(ds, m, 64);
    if ((d & 63) == 0) red[d >> 6] = ds;
    __syncthreads();
    if (d == 0) s_upd = sqrtf(red[0] + red[1] + red[2] + red[3] + 1e-24f);
    __syncthreads();
    const float upd_mag = s_upd;

    const bool  init  = read_bool(p_init, enc_pi, c);
    const bool  sinit = read_bool(s_init, enc_si, c);
    const float var   = p_var[c];
    const int   step  = read_step(p_step);

    const float progress = fminf(1.0f, (float)step * (1.0f / 2000.0f));
    const float mom = init ? (0.99f + 0.009f * expf(-var) * progress) : 0.99f;

    const float ema   = mom * oldp + (1.0f - mom) * cls;
    const float newp  = present ? (init ? ema : cls) : oldp;

    const float sh     = shadow[c * FDIM + d];
    const float sh_ema = 0.9999f * sh + 0.0001f * newp;
    const float newsh  = present ? (sinit ? sh_ema : newp) : sh;

    // flat f32 output layout (tuple order)
    const int O1 = NCLS * FDIM;           // new_var        (91)
    const int O2 = O1 + NCLS;             // new_shadow     (23296)
    const int O3 = O2 + NCLS * FDIM;      // new_initialized(91)
    const int O4 = O3 + NCLS;             // new_shadow_init(91)
    const int O5 = O4 + NCLS;             // new_count      (91)

    out[c * FDIM + d]       = newp;
    out[O2 + c * FDIM + d]  = newsh;
    if (d == 0) {
        const float newvar = (present && init) ? (0.99f * var + 0.01f * upd_mag) : var;
        out[O1 + c] = newvar;
        out[O3 + c] = (init || present)  ? 1.0f : 0.0f;
        out[O4 + c] = (sinit || present) ? 1.0f : 0.0f;
        out[O5 + c] = (float)(p_count[c] + (present ? 1 : 0));
    }
}

extern "C" void kernel_launch(void* const* d_in, const int* in_sizes, int n_in,
                              void* d_out, int out_size, void* d_ws, size_t ws_size,
                              hipStream_t stream) {
    const float* feats  = (const float*)d_in[0];
    const int*   labels = (const int*)d_in[1];
    const float* protos = (const float*)d_in[2];
    const void*  p_init = d_in[3];
    const float* p_var  = (const float*)d_in[4];
    const float* shadow = (const float*)d_in[5];
    const void*  s_init = d_in[6];
    const int*   p_cnt  = (const int*)d_in[7];
    const void*  p_step = d_in[8];
    const int nrows = in_sizes[1];

    float* g_sums = (float*)d_ws;
    unsigned int* g_counts = (unsigned int*)((char*)d_ws + (size_t)NCLS * FDIM * 4);
    const size_t accum_bytes = (size_t)NCLS * FDIM * 4 + (size_t)NCLS * 4;
    hipMemsetAsync(d_ws, 0, accum_bytes, stream);

    const size_t smem = (size_t)NCLS * FDIM * 4 + (size_t)NCLS * 4;
    seg_accum<<<BLOCKS1, THREADS1, smem, stream>>>(feats, labels, g_sums, g_counts, nrows);
    finalize<<<NCLS, FDIM, 0, stream>>>(g_sums, g_counts, protos, p_init, p_var,
                                        shadow, s_init, p_cnt, p_step, (float*)d_out);
}

// Round 2
// 213.071 us; speedup vs baseline: 1.0387x; 1.0387x over previous
//
#include <hip/hip_runtime.h>
#include <math.h>

#define NCLS 91
#define FDIM 256
#define BLOCKS1 256
#define THREADS1 1024
#define WAVES_PER_BLOCK (THREADS1 / 64)
#define TOTAL_WAVES (BLOCKS1 * WAVES_PER_BLOCK)

__device__ __forceinline__ float wave_sum64(float ss) {
    #pragma unroll
    for (int m = 1; m < 64; m <<= 1) ss += __shfl_xor(ss, m, 64);
    return ss;
}

// ---------------- kernel 1: normalize + segment-sum ----------------
// LDS bins per block: [NCLS][FDIM] floats in TRANSPOSED slot layout:
//   element d stored at slot (d&3)*64 + (d>>2) -> a wave's float4 components
//   land at slots {0,64,128,192}+lane: consecutive banks per component, no conflicts.
// All float accumulation uses unsafeAtomicAdd -> hardware ds_add_f32 /
// global_atomic_add_f32 (default atomicAdd(float*) emits a CAS retry loop,
// which was the 209us in R0: 6M CAS RMWs with 256-way address contention).
extern "C" __global__ void __launch_bounds__(THREADS1)
seg_accum(const float* __restrict__ feats, const int* __restrict__ labels,
          float* __restrict__ g_sums, unsigned int* __restrict__ g_counts,
          int nrows)
{
    extern __shared__ float smem[];
    float* bins = smem;                                          // NCLS*FDIM
    unsigned int* cbins = (unsigned int*)(smem + NCLS * FDIM);   // NCLS

    const int tid = threadIdx.x;
    for (int i = tid; i < NCLS * FDIM; i += THREADS1) bins[i] = 0.0f;
    for (int i = tid; i < NCLS; i += THREADS1) cbins[i] = 0u;
    __syncthreads();

    const int lane = tid & 63;
    const int gw = blockIdx.x * WAVES_PER_BLOCK + (tid >> 6);
    const size_t lofs = (size_t)lane * 4;

    int row = gw;
    // 4-row unroll: 4 independent float4 loads in flight per wave (covers HBM latency)
    for (; row + 3 * TOTAL_WAVES < nrows; row += 4 * TOTAL_WAVES) {
        const int r0 = row, r1 = row + TOTAL_WAVES, r2 = row + 2 * TOTAL_WAVES, r3 = row + 3 * TOTAL_WAVES;
        const float4 v0 = *reinterpret_cast<const float4*>(feats + (size_t)r0 * FDIM + lofs);
        const float4 v1 = *reinterpret_cast<const float4*>(feats + (size_t)r1 * FDIM + lofs);
        const float4 v2 = *reinterpret_cast<const float4*>(feats + (size_t)r2 * FDIM + lofs);
        const float4 v3 = *reinterpret_cast<const float4*>(feats + (size_t)r3 * FDIM + lofs);
        const int l0 = labels[r0], l1 = labels[r1], l2 = labels[r2], l3 = labels[r3];

        const float i0 = 1.0f / fmaxf(sqrtf(wave_sum64(v0.x*v0.x + v0.y*v0.y + v0.z*v0.z + v0.w*v0.w)), 1e-12f);
        const float i1 = 1.0f / fmaxf(sqrtf(wave_sum64(v1.x*v1.x + v1.y*v1.y + v1.z*v1.z + v1.w*v1.w)), 1e-12f);
        const float i2 = 1.0f / fmaxf(sqrtf(wave_sum64(v2.x*v2.x + v2.y*v2.y + v2.z*v2.z + v2.w*v2.w)), 1e-12f);
        const float i3 = 1.0f / fmaxf(sqrtf(wave_sum64(v3.x*v3.x + v3.y*v3.y + v3.z*v3.z + v3.w*v3.w)), 1e-12f);

        float* b0 = bins + l0 * FDIM;
        unsafeAtomicAdd(b0 + lane,       v0.x * i0);
        unsafeAtomicAdd(b0 + 64 + lane,  v0.y * i0);
        unsafeAtomicAdd(b0 + 128 + lane, v0.z * i0);
        unsafeAtomicAdd(b0 + 192 + lane, v0.w * i0);
        float* b1 = bins + l1 * FDIM;
        unsafeAtomicAdd(b1 + lane,       v1.x * i1);
        unsafeAtomicAdd(b1 + 64 + lane,  v1.y * i1);
        unsafeAtomicAdd(b1 + 128 + lane, v1.z * i1);
        unsafeAtomicAdd(b1 + 192 + lane, v1.w * i1);
        float* b2 = bins + l2 * FDIM;
        unsafeAtomicAdd(b2 + lane,       v2.x * i2);
        unsafeAtomicAdd(b2 + 64 + lane,  v2.y * i2);
        unsafeAtomicAdd(b2 + 128 + lane, v2.z * i2);
        unsafeAtomicAdd(b2 + 192 + lane, v2.w * i2);
        float* b3 = bins + l3 * FDIM;
        unsafeAtomicAdd(b3 + lane,       v3.x * i3);
        unsafeAtomicAdd(b3 + 64 + lane,  v3.y * i3);
        unsafeAtomicAdd(b3 + 128 + lane, v3.z * i3);
        unsafeAtomicAdd(b3 + 192 + lane, v3.w * i3);
        if (lane == 0) {
            atomicAdd(&cbins[l0], 1u); atomicAdd(&cbins[l1], 1u);
            atomicAdd(&cbins[l2], 1u); atomicAdd(&cbins[l3], 1u);
        }
    }
    for (; row < nrows; row += TOTAL_WAVES) {
        const float4 v = *reinterpret_cast<const float4*>(feats + (size_t)row * FDIM + lofs);
        const int lab = labels[row];
        const float inv = 1.0f / fmaxf(sqrtf(wave_sum64(v.x*v.x + v.y*v.y + v.z*v.z + v.w*v.w)), 1e-12f);
        float* b = bins + lab * FDIM;
        unsafeAtomicAdd(b + lane,       v.x * inv);
        unsafeAtomicAdd(b + 64 + lane,  v.y * inv);
        unsafeAtomicAdd(b + 128 + lane, v.z * inv);
        unsafeAtomicAdd(b + 192 + lane, v.w * inv);
        if (lane == 0) atomicAdd(&cbins[lab], 1u);
    }

    __syncthreads();
    // flush, rotated per-block so 256 blocks don't contend on the same addresses in lockstep
    const int rot = (blockIdx.x * 1024) % (NCLS * FDIM);
    for (int i = tid; i < NCLS * FDIM; i += THREADS1) {
        int s = i + rot; if (s >= NCLS * FDIM) s -= NCLS * FDIM;
        unsafeAtomicAdd(&g_sums[s], bins[s]);
    }
    for (int i = tid; i < NCLS; i += THREADS1)
        atomicAdd(&g_counts[i], cbins[i]);
}

// ---------------- bool / scalar dtype detection helpers ----------------
__device__ int detect_bool_enc(const void* p) {
    const unsigned int* u = (const unsigned int*)p;
    bool i32ok = true, f32ok = true;
    for (int i = 0; i < 22; ++i) {
        unsigned int w = u[i];
        if (w > 1u) i32ok = false;
        if (w != 0u && w != 0x3F800000u) f32ok = false;
    }
    return i32ok ? 1 : (f32ok ? 2 : 0);
}
__device__ bool read_bool(const void* p, int enc, int i) {
    if (enc == 1) return ((const unsigned int*)p)[i] != 0u;
    if (enc == 2) return ((const float*)p)[i] != 0.0f;
    return ((const unsigned char*)p)[i] != 0;
}
__device__ int read_step(const void* p) {
    unsigned int w = ((const unsigned int*)p)[0];
    int iv = (int)w;
    if (iv >= 0 && iv < 16777216) return iv;
    return (int)__uint_as_float(w);
}

// ---------------- kernel 2: per-class finalize ----------------
extern "C" __global__ void __launch_bounds__(FDIM)
finalize(const float* __restrict__ g_sums, const unsigned int* __restrict__ g_counts,
         const float* __restrict__ protos, const void* __restrict__ p_init,
         const float* __restrict__ p_var, const float* __restrict__ shadow,
         const void* __restrict__ s_init, const int* __restrict__ p_count,
         const void* __restrict__ p_step, float* __restrict__ out)
{
    const int c = blockIdx.x;
    const int d = threadIdx.x;

    __shared__ int enc_pi, enc_si;
    __shared__ float red[FDIM / 64];
    __shared__ float s_upd;
    if (d == 0) { enc_pi = detect_bool_enc(p_init); enc_si = detect_bool_enc(s_init); }
    __syncthreads();

    const unsigned int cnt = g_counts[c];
    const bool present = cnt > 0u;
    const float sum = g_sums[c * FDIM + ((d & 3) << 6) + (d >> 2)];   // un-permute
    const float cls = sum / fmaxf((float)cnt, 1.0f);
    const float oldp = protos[c * FDIM + d];

    const float diff = cls - oldp;
    float ds = wave_sum64(diff * diff);
    if ((d & 63) == 0) red[d >> 6] = ds;
    __syncthreads();
    if (d == 0) s_upd = sqrtf(red[0] + red[1] + red[2] + red[3] + 1e-24f);
    __syncthreads();
    const float upd_mag = s_upd;

    const bool  init  = read_bool(p_init, enc_pi, c);
    const bool  sinit = read_bool(s_init, enc_si, c);
    const float var   = p_var[c];
    const int   step  = read_step(p_step);

    const float progress = fminf(1.0f, (float)step * (1.0f / 2000.0f));
    const float mom = init ? (0.99f + 0.009f * expf(-var) * progress) : 0.99f;

    const float ema   = mom * oldp + (1.0f - mom) * cls;
    const float newp  = present ? (init ? ema : cls) : oldp;

    const float sh     = shadow[c * FDIM + d];
    const float sh_ema = 0.9999f * sh + 0.0001f * newp;
    const float newsh  = present ? (sinit ? sh_ema : newp) : sh;

    const int O1 = NCLS * FDIM;
    const int O2 = O1 + NCLS;
    const int O3 = O2 + NCLS * FDIM;
    const int O4 = O3 + NCLS;
    const int O5 = O4 + NCLS;

    out[c * FDIM + d]       = newp;
    out[O2 + c * FDIM + d]  = newsh;
    if (d == 0) {
        const float newvar = (present && init) ? (0.99f * var + 0.01f * upd_mag) : var;
        out[O1 + c] = newvar;
        out[O3 + c] = (init || present)  ? 1.0f : 0.0f;
        out[O4 + c] = (sinit || present) ? 1.0f : 0.0f;
        out[O5 + c] = (float)(p_count[c] + (present ? 1 : 0));
    }
}

extern "C" void kernel_launch(void* const* d_in, const int* in_sizes, int n_in,
                              void* d_out, int out_size, void* d_ws, size_t ws_size,
                              hipStream_t stream) {
    const float* feats  = (const float*)d_in[0];
    const int*   labels = (const int*)d_in[1];
    const float* protos = (const float*)d_in[2];
    const void*  p_init = d_in[3];
    const float* p_var  = (const float*)d_in[4];
    const float* shadow = (const float*)d_in[5];
    const void*  s_init = d_in[6];
    const int*   p_cnt  = (const int*)d_in[7];
    const void*  p_step = d_in[8];
    const int nrows = in_sizes[1];

    float* g_sums = (float*)d_ws;
    unsigned int* g_counts = (unsigned int*)((char*)d_ws + (size_t)NCLS * FDIM * 4);
    const size_t accum_bytes = (size_t)NCLS * FDIM * 4 + (size_t)NCLS * 4;
    hipMemsetAsync(d_ws, 0, accum_bytes, stream);

    const size_t smem = (size_t)NCLS * FDIM * 4 + (size_t)NCLS * 4;
    seg_accum<<<BLOCKS1, THREADS1, smem, stream>>>(feats, labels, g_sums, g_counts, nrows);
    finalize<<<NCLS, FDIM, 0, stream>>>(g_sums, g_counts, protos, p_init, p_var,
                                        shadow, s_init, p_cnt, p_step, (float*)d_out);
}

// Round 3
// 213.058 us; speedup vs baseline: 1.0387x; 1.0001x over previous
//
#include <hip/hip_runtime.h>
#include <math.h>

#define NCLS 91
#define FDIM 256
#define BINSZ (NCLS * FDIM)          // 23296
#define SLICE_F (BINSZ + 128)        // per-partial slice in floats (counts live at +BINSZ)
#define MAXPARTS 256
#define THREADS1 1024
#define WAVES_PER_BLOCK (THREADS1 / 64)

__device__ __forceinline__ float wave_sum64(float ss) {
    #pragma unroll
    for (int m = 1; m < 64; m <<= 1) ss += __shfl_xor(ss, m, 64);
    return ss;
}
__device__ __forceinline__ int wave_sum64_i(int v) {
    #pragma unroll
    for (int m = 1; m < 64; m <<= 1) v += __shfl_xor(v, m, 64);
    return v;
}

// ---------------- kernel 1: normalize + segment-sum into PRIVATE partial slice ----------------
// LDS bins in transposed slot layout: element d at slot (d&3)*64 + (d>>2).
// Flush = plain coalesced stores to this block's own ws slice (NO global atomics:
// R1 showed 6M contended global f32 atomics run at ~30 Gop/s memory-side RMW = 200us).
extern "C" __global__ void __launch_bounds__(THREADS1)
seg_accum(const float* __restrict__ feats, const int* __restrict__ labels,
          float* __restrict__ part, int nrows, int nparts)
{
    extern __shared__ float smem[];
    float* bins = smem;                                          // BINSZ
    unsigned int* cbins = (unsigned int*)(smem + BINSZ);         // NCLS

    const int tid = threadIdx.x;
    for (int i = tid; i < BINSZ; i += THREADS1) bins[i] = 0.0f;
    for (int i = tid; i < NCLS; i += THREADS1) cbins[i] = 0u;
    __syncthreads();

    const int lane = tid & 63;
    const int total_waves = nparts * WAVES_PER_BLOCK;
    const int gw = blockIdx.x * WAVES_PER_BLOCK + (tid >> 6);
    const size_t lofs = (size_t)lane * 4;

    int row = gw;
    for (; row + 3 * total_waves < nrows; row += 4 * total_waves) {
        const int r0 = row, r1 = row + total_waves, r2 = row + 2 * total_waves, r3 = row + 3 * total_waves;
        const float4 v0 = *reinterpret_cast<const float4*>(feats + (size_t)r0 * FDIM + lofs);
        const float4 v1 = *reinterpret_cast<const float4*>(feats + (size_t)r1 * FDIM + lofs);
        const float4 v2 = *reinterpret_cast<const float4*>(feats + (size_t)r2 * FDIM + lofs);
        const float4 v3 = *reinterpret_cast<const float4*>(feats + (size_t)r3 * FDIM + lofs);
        const int l0 = labels[r0], l1 = labels[r1], l2 = labels[r2], l3 = labels[r3];

        const float i0 = 1.0f / fmaxf(sqrtf(wave_sum64(v0.x*v0.x + v0.y*v0.y + v0.z*v0.z + v0.w*v0.w)), 1e-12f);
        const float i1 = 1.0f / fmaxf(sqrtf(wave_sum64(v1.x*v1.x + v1.y*v1.y + v1.z*v1.z + v1.w*v1.w)), 1e-12f);
        const float i2 = 1.0f / fmaxf(sqrtf(wave_sum64(v2.x*v2.x + v2.y*v2.y + v2.z*v2.z + v2.w*v2.w)), 1e-12f);
        const float i3 = 1.0f / fmaxf(sqrtf(wave_sum64(v3.x*v3.x + v3.y*v3.y + v3.z*v3.z + v3.w*v3.w)), 1e-12f);

        float* b0 = bins + l0 * FDIM;
        unsafeAtomicAdd(b0 + lane,       v0.x * i0);
        unsafeAtomicAdd(b0 + 64 + lane,  v0.y * i0);
        unsafeAtomicAdd(b0 + 128 + lane, v0.z * i0);
        unsafeAtomicAdd(b0 + 192 + lane, v0.w * i0);
        float* b1 = bins + l1 * FDIM;
        unsafeAtomicAdd(b1 + lane,       v1.x * i1);
        unsafeAtomicAdd(b1 + 64 + lane,  v1.y * i1);
        unsafeAtomicAdd(b1 + 128 + lane, v1.z * i1);
        unsafeAtomicAdd(b1 + 192 + lane, v1.w * i1);
        float* b2 = bins + l2 * FDIM;
        unsafeAtomicAdd(b2 + lane,       v2.x * i2);
        unsafeAtomicAdd(b2 + 64 + lane,  v2.y * i2);
        unsafeAtomicAdd(b2 + 128 + lane, v2.z * i2);
        unsafeAtomicAdd(b2 + 192 + lane, v2.w * i2);
        float* b3 = bins + l3 * FDIM;
        unsafeAtomicAdd(b3 + lane,       v3.x * i3);
        unsafeAtomicAdd(b3 + 64 + lane,  v3.y * i3);
        unsafeAtomicAdd(b3 + 128 + lane, v3.z * i3);
        unsafeAtomicAdd(b3 + 192 + lane, v3.w * i3);
        if (lane == 0) {
            atomicAdd(&cbins[l0], 1u); atomicAdd(&cbins[l1], 1u);
            atomicAdd(&cbins[l2], 1u); atomicAdd(&cbins[l3], 1u);
        }
    }
    for (; row < nrows; row += total_waves) {
        const float4 v = *reinterpret_cast<const float4*>(feats + (size_t)row * FDIM + lofs);
        const int lab = labels[row];
        const float inv = 1.0f / fmaxf(sqrtf(wave_sum64(v.x*v.x + v.y*v.y + v.z*v.z + v.w*v.w)), 1e-12f);
        float* b = bins + lab * FDIM;
        unsafeAtomicAdd(b + lane,       v.x * inv);
        unsafeAtomicAdd(b + 64 + lane,  v.y * inv);
        unsafeAtomicAdd(b + 128 + lane, v.z * inv);
        unsafeAtomicAdd(b + 192 + lane, v.w * inv);
        if (lane == 0) atomicAdd(&cbins[lab], 1u);
    }

    __syncthreads();
    // plain coalesced flush to this block's private slice
    float* my = part + (size_t)blockIdx.x * SLICE_F;
    for (int i = tid; i < BINSZ; i += THREADS1) my[i] = bins[i];
    unsigned int* myc = (unsigned int*)(my + BINSZ);
    for (int i = tid; i < NCLS; i += THREADS1) myc[i] = cbins[i];
}

// ---------------- bool / scalar dtype detection helpers ----------------
__device__ int detect_bool_enc(const void* p) {
    const unsigned int* u = (const unsigned int*)p;
    bool i32ok = true, f32ok = true;
    for (int i = 0; i < 22; ++i) {
        unsigned int w = u[i];
        if (w > 1u) i32ok = false;
        if (w != 0u && w != 0x3F800000u) f32ok = false;
    }
    return i32ok ? 1 : (f32ok ? 2 : 0);
}
__device__ bool read_bool(const void* p, int enc, int i) {
    if (enc == 1) return ((const unsigned int*)p)[i] != 0u;
    if (enc == 2) return ((const float*)p)[i] != 0.0f;
    return ((const unsigned char*)p)[i] != 0;
}
__device__ int read_step(const void* p) {
    unsigned int w = ((const unsigned int*)p)[0];
    int iv = (int)w;
    if (iv >= 0 && iv < 16777216) return iv;
    return (int)__uint_as_float(w);
}

// ---------------- kernel 2: reduce partials + per-class finalize ----------------
extern "C" __global__ void __launch_bounds__(FDIM)
finalize(const float* __restrict__ part, int nparts,
         const float* __restrict__ protos, const void* __restrict__ p_init,
         const float* __restrict__ p_var, const float* __restrict__ shadow,
         const void* __restrict__ s_init, const int* __restrict__ p_count,
         const void* __restrict__ p_step, float* __restrict__ out)
{
    const int c = blockIdx.x;
    const int d = threadIdx.x;

    __shared__ int enc_pi, enc_si;
    __shared__ float red[FDIM / 64];
    __shared__ int credi[FDIM / 64];
    __shared__ float s_upd;
    __shared__ unsigned int s_cnt;
    if (d == 0) { enc_pi = detect_bool_enc(p_init); enc_si = detect_bool_enc(s_init); }

    // reduce this class's sums across partials (un-permuting the slot layout)
    const int slot = c * FDIM + ((d & 3) << 6) + (d >> 2);
    float sum = 0.0f;
    {
        float a0 = 0.f, a1 = 0.f, a2 = 0.f, a3 = 0.f;
        int p = 0;
        for (; p + 3 < nparts; p += 4) {
            a0 += part[(size_t)(p + 0) * SLICE_F + slot];
            a1 += part[(size_t)(p + 1) * SLICE_F + slot];
            a2 += part[(size_t)(p + 2) * SLICE_F + slot];
            a3 += part[(size_t)(p + 3) * SLICE_F + slot];
        }
        for (; p < nparts; ++p) a0 += part[(size_t)p * SLICE_F + slot];
        sum = (a0 + a1) + (a2 + a3);
    }

    // reduce counts: thread d reads partial d's count (d < nparts), block-reduce
    int cpart = 0;
    if (d < nparts)
        cpart = (int)((const unsigned int*)(part + (size_t)d * SLICE_F + BINSZ))[c];
    int cw = wave_sum64_i(cpart);
    if ((d & 63) == 0) credi[d >> 6] = cw;
    __syncthreads();
    if (d == 0) s_cnt = (unsigned int)(credi[0] + credi[1] + credi[2] + credi[3]);
    __syncthreads();

    const unsigned int cnt = s_cnt;
    const bool present = cnt > 0u;
    const float cls = sum / fmaxf((float)cnt, 1.0f);
    const float oldp = protos[c * FDIM + d];

    const float diff = cls - oldp;
    float ds = wave_sum64(diff * diff);
    if ((d & 63) == 0) red[d >> 6] = ds;
    __syncthreads();
    if (d == 0) s_upd = sqrtf(red[0] + red[1] + red[2] + red[3] + 1e-24f);
    __syncthreads();
    const float upd_mag = s_upd;

    const bool  init  = read_bool(p_init, enc_pi, c);
    const bool  sinit = read_bool(s_init, enc_si, c);
    const float var   = p_var[c];
    const int   step  = read_step(p_step);

    const float progress = fminf(1.0f, (float)step * (1.0f / 2000.0f));
    const float mom = init ? (0.99f + 0.009f * expf(-var) * progress) : 0.99f;

    const float ema   = mom * oldp + (1.0f - mom) * cls;
    const float newp  = present ? (init ? ema : cls) : oldp;

    const float sh     = shadow[c * FDIM + d];
    const float sh_ema = 0.9999f * sh + 0.0001f * newp;
    const float newsh  = present ? (sinit ? sh_ema : newp) : sh;

    const int O1 = NCLS * FDIM;
    const int O2 = O1 + NCLS;
    const int O3 = O2 + NCLS * FDIM;
    const int O4 = O3 + NCLS;
    const int O5 = O4 + NCLS;

    out[c * FDIM + d]       = newp;
    out[O2 + c * FDIM + d]  = newsh;
    if (d == 0) {
        const float newvar = (present && init) ? (0.99f * var + 0.01f * upd_mag) : var;
        out[O1 + c] = newvar;
        out[O3 + c] = (init || present)  ? 1.0f : 0.0f;
        out[O4 + c] = (sinit || present) ? 1.0f : 0.0f;
        out[O5 + c] = (float)(p_count[c] + (present ? 1 : 0));
    }
}

extern "C" void kernel_launch(void* const* d_in, const int* in_sizes, int n_in,
                              void* d_out, int out_size, void* d_ws, size_t ws_size,
                              hipStream_t stream) {
    const float* feats  = (const float*)d_in[0];
    const int*   labels = (const int*)d_in[1];
    const float* protos = (const float*)d_in[2];
    const void*  p_init = d_in[3];
    const float* p_var  = (const float*)d_in[4];
    const float* shadow = (const float*)d_in[5];
    const void*  s_init = d_in[6];
    const int*   p_cnt  = (const int*)d_in[7];
    const void*  p_step = d_in[8];
    const int nrows = in_sizes[1];

    int nparts = (int)(ws_size / ((size_t)SLICE_F * 4));
    if (nparts > MAXPARTS) nparts = MAXPARTS;
    if (nparts < 1) nparts = 1;

    float* part = (float*)d_ws;
    const size_t smem = (size_t)BINSZ * 4 + (size_t)NCLS * 4;
    seg_accum<<<nparts, THREADS1, smem, stream>>>(feats, labels, part, nrows, nparts);
    finalize<<<NCLS, FDIM, 0, stream>>>(part, nparts, protos, p_init, p_var,
                                        shadow, s_init, p_cnt, p_step, (float*)d_out);
}

// Round 4
// 84.677 us; speedup vs baseline: 2.6136x; 2.5161x over previous
//
#include <hip/hip_runtime.h>
#include <math.h>

#define NCLS 91
#define FDIM 256
#define BINSZ (NCLS * FDIM)        // 23296

// ---- workspace layout (4-byte units) ----
// [0 .. BINSZ)           g_sums   (f32, zeroed each call)
// [BINSZ .. +91)         hist     (u32, zeroed)
// [BINSZ+91 .. +91)      cursor   (u32, zeroed)
// [BINSZ+182 .. +nrows)  sorted   (u32 row indices, label-major)
// [.. +nrows)            slab     (i32 label of sorted row)
#define WS_HIST   BINSZ
#define WS_CURSOR (BINSZ + NCLS)
#define WS_SORTED (BINSZ + 2 * NCLS)

__device__ __forceinline__ float wave_sum64(float ss) {
    #pragma unroll
    for (int m = 1; m < 64; m <<= 1) ss += __shfl_xor(ss, m, 64);
    return ss;
}

// ---------------- K1: global label histogram ----------------
#define HT 256
extern "C" __global__ void __launch_bounds__(HT)
hist_k(const int* __restrict__ labels, unsigned int* __restrict__ hist, int nrows)
{
    __shared__ unsigned int lh[NCLS];
    const int tid = threadIdx.x;
    for (int i = tid; i < NCLS; i += HT) lh[i] = 0u;
    __syncthreads();
    for (int i = blockIdx.x * HT + tid; i < nrows; i += gridDim.x * HT)
        atomicAdd(&lh[labels[i]], 1u);                 // native ds_add_u32
    __syncthreads();
    for (int i = tid; i < NCLS; i += HT)
        if (lh[i]) atomicAdd(&hist[i], lh[i]);
}

// ---------------- K2: exclusive prefix -> cursor ----------------
extern "C" __global__ void __launch_bounds__(128)
prefix_k(const unsigned int* __restrict__ hist, unsigned int* __restrict__ cursor)
{
    __shared__ unsigned int h[NCLS];
    const int tid = threadIdx.x;
    if (tid < NCLS) h[tid] = hist[tid];
    __syncthreads();
    if (tid == 0) {
        unsigned int s = 0;
        for (int c = 0; c < NCLS; ++c) { unsigned int v = h[c]; h[c] = s; s += v; }
    }
    __syncthreads();
    if (tid < NCLS) cursor[tid] = h[tid];
}

// ---------------- K3: stable-ish counting-sort scatter ----------------
#define SCHUNK 2048
extern "C" __global__ void __launch_bounds__(HT)
scatter_k(const int* __restrict__ labels, unsigned int* __restrict__ cursor,
          unsigned int* __restrict__ sorted, int* __restrict__ slab, int nrows)
{
    __shared__ int ll[SCHUNK];
    __shared__ unsigned int lh[NCLS];
    __shared__ unsigned int base[NCLS];
    const int tid = threadIdx.x;
    const int c0 = blockIdx.x * SCHUNK;
    const int cn = min(SCHUNK, nrows - c0);
    if (cn <= 0) return;

    for (int i = tid; i < NCLS; i += HT) lh[i] = 0u;
    __syncthreads();
    for (int i = tid; i < cn; i += HT) {
        const int l = labels[c0 + i];
        ll[i] = l;
        atomicAdd(&lh[l], 1u);
    }
    __syncthreads();
    for (int i = tid; i < NCLS; i += HT) {
        const unsigned int n = lh[i];
        base[i] = n ? atomicAdd(&cursor[i], n) : 0u;   // reserve block range
        lh[i] = 0u;                                    // reuse as intra-block rank
    }
    __syncthreads();
    for (int i = tid; i < cn; i += HT) {
        const int l = ll[i];
        const unsigned int rank = atomicAdd(&lh[l], 1u);
        const unsigned int pos = base[l] + rank;
        sorted[pos] = (unsigned int)(c0 + i);
        slab[pos] = l;
    }
}

// ---------------- K4: main pass — normalize + register-accumulated segment sum ----------------
#define MT 256
#define MWAVES (MT / 64)
extern "C" __global__ void __launch_bounds__(MT)
mainpass(const float* __restrict__ feats, const unsigned int* __restrict__ sorted,
         const int* __restrict__ slab, float* __restrict__ g_sums, int nrows)
{
    const int lane = threadIdx.x & 63;
    const int wid = blockIdx.x * MWAVES + (threadIdx.x >> 6);
    const int nw = gridDim.x * MWAVES;
    const int per = (nrows + nw - 1) / nw;
    const int i0 = wid * per;
    const int i1 = min(nrows, i0 + per);
    if (i0 >= i1) return;

    float ax = 0.f, ay = 0.f, az = 0.f, aw = 0.f;
    int cur = -1;
    for (int i = i0; i < i1; ++i) {
        const int lab = slab[i];                       // wave-uniform broadcast load
        if (lab != cur) {                              // wave-uniform branch
            if (cur >= 0) {
                float* g = g_sums + cur * FDIM + lane * 4;
                unsafeAtomicAdd(g + 0, ax);
                unsafeAtomicAdd(g + 1, ay);
                unsafeAtomicAdd(g + 2, az);
                unsafeAtomicAdd(g + 3, aw);
            }
            ax = ay = az = aw = 0.f;
            cur = lab;
        }
        const unsigned int r = sorted[i];
        const float4 v = *reinterpret_cast<const float4*>(
            feats + (size_t)r * FDIM + (size_t)lane * 4);
        const float ss = wave_sum64(v.x * v.x + v.y * v.y + v.z * v.z + v.w * v.w);
        const float inv = 1.0f / fmaxf(sqrtf(ss), 1e-12f);
        ax = fmaf(v.x, inv, ax);
        ay = fmaf(v.y, inv, ay);
        az = fmaf(v.z, inv, az);
        aw = fmaf(v.w, inv, aw);
    }
    if (cur >= 0) {
        float* g = g_sums + cur * FDIM + lane * 4;
        unsafeAtomicAdd(g + 0, ax);
        unsafeAtomicAdd(g + 1, ay);
        unsafeAtomicAdd(g + 2, az);
        unsafeAtomicAdd(g + 3, aw);
    }
}

// ---------------- bool / scalar dtype detection ----------------
__device__ int detect_bool_enc(const void* p) {
    const unsigned int* u = (const unsigned int*)p;
    bool i32ok = true, f32ok = true;
    for (int i = 0; i < 22; ++i) {
        unsigned int w = u[i];
        if (w > 1u) i32ok = false;
        if (w != 0u && w != 0x3F800000u) f32ok = false;
    }
    return i32ok ? 1 : (f32ok ? 2 : 0);
}
__device__ bool read_bool(const void* p, int enc, int i) {
    if (enc == 1) return ((const unsigned int*)p)[i] != 0u;
    if (enc == 2) return ((const float*)p)[i] != 0.0f;
    return ((const unsigned char*)p)[i] != 0;
}
__device__ int read_step(const void* p) {
    unsigned int w = ((const unsigned int*)p)[0];
    int iv = (int)w;
    if (iv >= 0 && iv < 16777216) return iv;
    return (int)__uint_as_float(w);
}

// ---------------- K5: per-class finalize ----------------
extern "C" __global__ void __launch_bounds__(FDIM)
finalize(const float* __restrict__ g_sums, const unsigned int* __restrict__ hist,
         const float* __restrict__ protos, const void* __restrict__ p_init,
         const float* __restrict__ p_var, const float* __restrict__ shadow,
         const void* __restrict__ s_init, const int* __restrict__ p_count,
         const void* __restrict__ p_step, float* __restrict__ out)
{
    const int c = blockIdx.x;
    const int d = threadIdx.x;

    __shared__ int enc_pi, enc_si;
    __shared__ float red[FDIM / 64];
    __shared__ float s_upd;
    if (d == 0) { enc_pi = detect_bool_enc(p_init); enc_si = detect_bool_enc(s_init); }
    __syncthreads();

    const unsigned int cnt = hist[c];
    const bool present = cnt > 0u;
    const float cls = g_sums[c * FDIM + d] / fmaxf((float)cnt, 1.0f);
    const float oldp = protos[c * FDIM + d];

    const float diff = cls - oldp;
    float ds = wave_sum64(diff * diff);
    if ((d & 63) == 0) red[d >> 6] = ds;
    __syncthreads();
    if (d == 0) s_upd = sqrtf(red[0] + red[1] + red[2] + red[3] + 1e-24f);
    __syncthreads();
    const float upd_mag = s_upd;

    const bool  init  = read_bool(p_init, enc_pi, c);
    const bool  sinit = read_bool(s_init, enc_si, c);
    const float var   = p_var[c];
    const int   step  = read_step(p_step);

    const float progress = fminf(1.0f, (float)step * (1.0f / 2000.0f));
    const float mom = init ? (0.99f + 0.009f * expf(-var) * progress) : 0.99f;

    const float ema   = mom * oldp + (1.0f - mom) * cls;
    const float newp  = present ? (init ? ema : cls) : oldp;

    const float sh     = shadow[c * FDIM + d];
    const float sh_ema = 0.9999f * sh + 0.0001f * newp;
    const float newsh  = present ? (sinit ? sh_ema : newp) : sh;

    const int O1 = NCLS * FDIM;
    const int O2 = O1 + NCLS;
    const int O3 = O2 + NCLS * FDIM;
    const int O4 = O3 + NCLS;
    const int O5 = O4 + NCLS;

    out[c * FDIM + d]       = newp;
    out[O2 + c * FDIM + d]  = newsh;
    if (d == 0) {
        const float newvar = (present && init) ? (0.99f * var + 0.01f * upd_mag) : var;
        out[O1 + c] = newvar;
        out[O3 + c] = (init || present)  ? 1.0f : 0.0f;
        out[O4 + c] = (sinit || present) ? 1.0f : 0.0f;
        out[O5 + c] = (float)(p_count[c] + (present ? 1 : 0));
    }
}

extern "C" void kernel_launch(void* const* d_in, const int* in_sizes, int n_in,
                              void* d_out, int out_size, void* d_ws, size_t ws_size,
                              hipStream_t stream) {
    const float* feats  = (const float*)d_in[0];
    const int*   labels = (const int*)d_in[1];
    const float* protos = (const float*)d_in[2];
    const void*  p_init = d_in[3];
    const float* p_var  = (const float*)d_in[4];
    const float* shadow = (const float*)d_in[5];
    const void*  s_init = d_in[6];
    const int*   p_cnt  = (const int*)d_in[7];
    const void*  p_step = d_in[8];
    const int nrows = in_sizes[1];

    float*        g_sums = (float*)d_ws;
    unsigned int* hist   = (unsigned int*)d_ws + WS_HIST;
    unsigned int* cursor = (unsigned int*)d_ws + WS_CURSOR;
    unsigned int* sorted = (unsigned int*)d_ws + WS_SORTED;
    int*          slab   = (int*)((unsigned int*)d_ws + WS_SORTED + nrows);

    // zero accumulators (g_sums + hist + cursor are contiguous at ws start)
    hipMemsetAsync(d_ws, 0, (size_t)(BINSZ + 2 * NCLS) * 4, stream);

    const int hist_blocks = 64;
    hist_k<<<hist_blocks, HT, 0, stream>>>(labels, hist, nrows);
    prefix_k<<<1, 128, 0, stream>>>(hist, cursor);
    const int scat_blocks = (nrows + SCHUNK - 1) / SCHUNK;
    scatter_k<<<scat_blocks, HT, 0, stream>>>(labels, cursor, sorted, slab, nrows);
    const int main_blocks = 2048;
    mainpass<<<main_blocks, MT, 0, stream>>>(feats, sorted, slab, g_sums, nrows);
    finalize<<<NCLS, FDIM, 0, stream>>>(g_sums, hist, protos, p_init, p_var,
                                        shadow, s_init, p_cnt, p_step, (float*)d_out);
}

// Round 5
// 66.637 us; speedup vs baseline: 3.3211x; 1.2707x over previous
//
#include <hip/hip_runtime.h>
#include <math.h>

#define NCLS 91
#define FDIM 256
#define BINSZ (NCLS * FDIM)        // 23296

// ---- workspace layout (4-byte units) ----
#define WS_HIST   BINSZ
#define WS_CURSOR (BINSZ + NCLS)
#define WS_SORTED (BINSZ + 2 * NCLS)

__device__ __forceinline__ float wave_sum64(float ss) {
    #pragma unroll
    for (int m = 1; m < 64; m <<= 1) ss += __shfl_xor(ss, m, 64);
    return ss;
}

// ---------------- K1: global label histogram ----------------
#define HT 256
extern "C" __global__ void __launch_bounds__(HT)
hist_k(const int* __restrict__ labels, unsigned int* __restrict__ hist, int nrows)
{
    __shared__ unsigned int lh[NCLS];
    const int tid = threadIdx.x;
    for (int i = tid; i < NCLS; i += HT) lh[i] = 0u;
    __syncthreads();
    for (int i = blockIdx.x * HT + tid; i < nrows; i += gridDim.x * HT)
        atomicAdd(&lh[labels[i]], 1u);
    __syncthreads();
    for (int i = tid; i < NCLS; i += HT)
        if (lh[i]) atomicAdd(&hist[i], lh[i]);
}

// ---------------- K2: exclusive prefix -> cursor ----------------
extern "C" __global__ void __launch_bounds__(128)
prefix_k(const unsigned int* __restrict__ hist, unsigned int* __restrict__ cursor)
{
    __shared__ unsigned int h[NCLS];
    const int tid = threadIdx.x;
    if (tid < NCLS) h[tid] = hist[tid];
    __syncthreads();
    if (tid == 0) {
        unsigned int s = 0;
        for (int c = 0; c < NCLS; ++c) { unsigned int v = h[c]; h[c] = s; s += v; }
    }
    __syncthreads();
    if (tid < NCLS) cursor[tid] = h[tid];
}

// ---------------- K3: counting-sort scatter ----------------
#define SCHUNK 2048
extern "C" __global__ void __launch_bounds__(HT)
scatter_k(const int* __restrict__ labels, unsigned int* __restrict__ cursor,
          unsigned int* __restrict__ sorted, int* __restrict__ slab, int nrows)
{
    __shared__ int ll[SCHUNK];
    __shared__ unsigned int lh[NCLS];
    __shared__ unsigned int base[NCLS];
    const int tid = threadIdx.x;
    const int c0 = blockIdx.x * SCHUNK;
    const int cn = min(SCHUNK, nrows - c0);
    if (cn <= 0) return;

    for (int i = tid; i < NCLS; i += HT) lh[i] = 0u;
    __syncthreads();
    for (int i = tid; i < cn; i += HT) {
        const int l = labels[c0 + i];
        ll[i] = l;
        atomicAdd(&lh[l], 1u);
    }
    __syncthreads();
    for (int i = tid; i < NCLS; i += HT) {
        const unsigned int n = lh[i];
        base[i] = n ? atomicAdd(&cursor[i], n) : 0u;
        lh[i] = 0u;
    }
    __syncthreads();
    for (int i = tid; i < cn; i += HT) {
        const int l = ll[i];
        const unsigned int rank = atomicAdd(&lh[l], 1u);
        const unsigned int pos = base[l] + rank;
        sorted[pos] = (unsigned int)(c0 + i);
        slab[pos] = l;
    }
}

// ---------------- K4: main pass ----------------
// 256 blocks x 1024 thr. Each block owns a CONTIGUOUS run of sorted rows ->
// touches only classes [slab[first], slab[last]] (typically 2-3 of 91).
// Waves register-accumulate 32 rows (8 loads in flight via SGPR-based addrs),
// flush label-transitions into block LDS bins (ds_add), block flushes ONLY the
// touched span to g_sums with global atomics: ~200k atomics total vs R3's 2.1M
// (global f32 atomics measured ~30 G/s in R1 -> that WAS the 80us).
#define MPB 256
#define MPT 1024
#define MPW (MPT / 64)
extern "C" __global__ void __launch_bounds__(MPT)
mainpass(const float* __restrict__ feats, const unsigned int* __restrict__ sorted,
         const int* __restrict__ slab, float* __restrict__ g_sums, int nrows)
{
    __shared__ float bins[BINSZ];
    __shared__ int s_cmin, s_cmax;
    const int tid = threadIdx.x;
    for (int i = tid; i < BINSZ; i += MPT) bins[i] = 0.0f;

    const int rpb = (nrows + gridDim.x - 1) / gridDim.x;
    const int blk0 = min(nrows, (int)blockIdx.x * rpb);
    const int blk1 = min(nrows, blk0 + rpb);
    if (tid == 0) {
        if (blk0 < blk1) { s_cmin = slab[blk0]; s_cmax = slab[blk1 - 1]; }
        else { s_cmin = 0; s_cmax = -1; }
    }
    __syncthreads();

    const int lane = tid & 63;
    const int w = tid >> 6;
    const int rpw = (rpb + MPW - 1) / MPW;
    const int i0w = min(blk1, blk0 + w * rpw);
    const int i1w = min(blk1, i0w + rpw);

    float ax = 0.f, ay = 0.f, az = 0.f, aww = 0.f;
    int cur = -1;
    for (int c0 = i0w; c0 < i1w; c0 += 64) {
        const int m = min(64, i1w - c0);
        const int pl = (lane < m) ? slab[c0 + lane] : -1;
        const int pr = (lane < m) ? (int)sorted[c0 + lane] : 0;
        for (int b0 = 0; b0 < m; b0 += 8) {
            const int n = min(8, m - b0);
            float4 v[8];
            int lj[8];
            #pragma unroll
            for (int j = 0; j < 8; ++j) {
                if (j < n) {
                    const int r = __builtin_amdgcn_readfirstlane(__shfl(pr, b0 + j));
                    lj[j] = __builtin_amdgcn_readfirstlane(__shfl(pl, b0 + j));
                    v[j] = *reinterpret_cast<const float4*>(
                        feats + (size_t)r * FDIM + (size_t)lane * 4);
                }
            }
            #pragma unroll
            for (int j = 0; j < 8; ++j) {
                if (j < n) {
                    if (lj[j] != cur) {                    // wave-uniform (scalar)
                        if (cur >= 0) {
                            float* b = bins + cur * FDIM;  // transposed slot layout
                            unsafeAtomicAdd(b + lane,       ax);
                            unsafeAtomicAdd(b + 64 + lane,  ay);
                            unsafeAtomicAdd(b + 128 + lane, az);
                            unsafeAtomicAdd(b + 192 + lane, aww);
                        }
                        ax = ay = az = aww = 0.f;
                        cur = lj[j];
                    }
                    const float ss = wave_sum64(v[j].x * v[j].x + v[j].y * v[j].y +
                                                v[j].z * v[j].z + v[j].w * v[j].w);
                    const float inv = 1.0f / fmaxf(sqrtf(ss), 1e-12f);
                    ax = fmaf(v[j].x, inv, ax);
                    ay = fmaf(v[j].y, inv, ay);
                    az = fmaf(v[j].z, inv, az);
                    aww = fmaf(v[j].w, inv, aww);
                }
            }
        }
    }
    if (cur >= 0) {
        float* b = bins + cur * FDIM;
        unsafeAtomicAdd(b + lane,       ax);
        unsafeAtomicAdd(b + 64 + lane,  ay);
        unsafeAtomicAdd(b + 128 + lane, az);
        unsafeAtomicAdd(b + 192 + lane, aww);
    }

    __syncthreads();
    const int cmin = s_cmin, cmax = s_cmax;
    if (cmax >= cmin) {
        const int base = cmin * FDIM;
        const int tot = (cmax - cmin + 1) * FDIM;
        for (int i = tid; i < tot; i += MPT) {
            const float vv = bins[base + i];
            if (vv != 0.0f) unsafeAtomicAdd(&g_sums[base + i], vv);
        }
    }
}

// ---------------- bool / scalar dtype detection ----------------
__device__ int detect_bool_enc(const void* p) {
    const unsigned int* u = (const unsigned int*)p;
    bool i32ok = true, f32ok = true;
    for (int i = 0; i < 22; ++i) {
        unsigned int w = u[i];
        if (w > 1u) i32ok = false;
        if (w != 0u && w != 0x3F800000u) f32ok = false;
    }
    return i32ok ? 1 : (f32ok ? 2 : 0);
}
__device__ bool read_bool(const void* p, int enc, int i) {
    if (enc == 1) return ((const unsigned int*)p)[i] != 0u;
    if (enc == 2) return ((const float*)p)[i] != 0.0f;
    return ((const unsigned char*)p)[i] != 0;
}
__device__ int read_step(const void* p) {
    unsigned int w = ((const unsigned int*)p)[0];
    int iv = (int)w;
    if (iv >= 0 && iv < 16777216) return iv;
    return (int)__uint_as_float(w);
}

// ---------------- K5: per-class finalize ----------------
extern "C" __global__ void __launch_bounds__(FDIM)
finalize(const float* __restrict__ g_sums, const unsigned int* __restrict__ hist,
         const float* __restrict__ protos, const void* __restrict__ p_init,
         const float* __restrict__ p_var, const float* __restrict__ shadow,
         const void* __restrict__ s_init, const int* __restrict__ p_count,
         const void* __restrict__ p_step, float* __restrict__ out)
{
    const int c = blockIdx.x;
    const int d = threadIdx.x;

    __shared__ int enc_pi, enc_si;
    __shared__ float red[FDIM / 64];
    __shared__ float s_upd;
    if (d == 0) { enc_pi = detect_bool_enc(p_init); enc_si = detect_bool_enc(s_init); }
    __syncthreads();

    const unsigned int cnt = hist[c];
    const bool present = cnt > 0u;
    // un-permute the transposed slot layout
    const float sum = g_sums[c * FDIM + ((d & 3) << 6) + (d >> 2)];
    const float cls = sum / fmaxf((float)cnt, 1.0f);
    const float oldp = protos[c * FDIM + d];

    const float diff = cls - oldp;
    float ds = wave_sum64(diff * diff);
    if ((d & 63) == 0) red[d >> 6] = ds;
    __syncthreads();
    if (d == 0) s_upd = sqrtf(red[0] + red[1] + red[2] + red[3] + 1e-24f);
    __syncthreads();
    const float upd_mag = s_upd;

    const bool  init  = read_bool(p_init, enc_pi, c);
    const bool  sinit = read_bool(s_init, enc_si, c);
    const float var   = p_var[c];
    const int   step  = read_step(p_step);

    const float progress = fminf(1.0f, (float)step * (1.0f / 2000.0f));
    const float mom = init ? (0.99f + 0.009f * expf(-var) * progress) : 0.99f;

    const float ema   = mom * oldp + (1.0f - mom) * cls;
    const float newp  = present ? (init ? ema : cls) : oldp;

    const float sh     = shadow[c * FDIM + d];
    const float sh_ema = 0.9999f * sh + 0.0001f * newp;
    const float newsh  = present ? (sinit ? sh_ema : newp) : sh;

    const int O1 = NCLS * FDIM;
    const int O2 = O1 + NCLS;
    const int O3 = O2 + NCLS * FDIM;
    const int O4 = O3 + NCLS;
    const int O5 = O4 + NCLS;

    out[c * FDIM + d]       = newp;
    out[O2 + c * FDIM + d]  = newsh;
    if (d == 0) {
        const float newvar = (present && init) ? (0.99f * var + 0.01f * upd_mag) : var;
        out[O1 + c] = newvar;
        out[O3 + c] = (init || present)  ? 1.0f : 0.0f;
        out[O4 + c] = (sinit || present) ? 1.0f : 0.0f;
        out[O5 + c] = (float)(p_count[c] + (present ? 1 : 0));
    }
}

extern "C" void kernel_launch(void* const* d_in, const int* in_sizes, int n_in,
                              void* d_out, int out_size, void* d_ws, size_t ws_size,
                              hipStream_t stream) {
    const float* feats  = (const float*)d_in[0];
    const int*   labels = (const int*)d_in[1];
    const float* protos = (const float*)d_in[2];
    const void*  p_init = d_in[3];
    const float* p_var  = (const float*)d_in[4];
    const float* shadow = (const float*)d_in[5];
    const void*  s_init = d_in[6];
    const int*   p_cnt  = (const int*)d_in[7];
    const void*  p_step = d_in[8];
    const int nrows = in_sizes[1];

    float*        g_sums = (float*)d_ws;
    unsigned int* hist   = (unsigned int*)d_ws + WS_HIST;
    unsigned int* cursor = (unsigned int*)d_ws + WS_CURSOR;
    unsigned int* sorted = (unsigned int*)d_ws + WS_SORTED;
    int*          slab   = (int*)((unsigned int*)d_ws + WS_SORTED + nrows);

    hipMemsetAsync(d_ws, 0, (size_t)(BINSZ + 2 * NCLS) * 4, stream);

    hist_k<<<64, HT, 0, stream>>>(labels, hist, nrows);
    prefix_k<<<1, 128, 0, stream>>>(hist, cursor);
    const int scat_blocks = (nrows + SCHUNK - 1) / SCHUNK;
    scatter_k<<<scat_blocks, HT, 0, stream>>>(labels, cursor, sorted, slab, nrows);
    mainpass<<<MPB, MPT, 0, stream>>>(feats, sorted, slab, g_sums, nrows);
    finalize<<<NCLS, FDIM, 0, stream>>>(g_sums, hist, protos, p_init, p_var,
                                        shadow, s_init, p_cnt, p_step, (float*)d_out);
}